// Round 3
// baseline (1117.038 us; speedup 1.0000x reference)
//
#include <hip/hip_runtime.h>
#include <stdint.h>

#define H 512
#define MTILE 64
#define NBLK 8192
#define STEPC (2.4f / 63.0f)

typedef _Float16 half8 __attribute__((ext_vector_type(8)));
typedef _Float16 half4_t __attribute__((ext_vector_type(4)));
typedef float floatx4 __attribute__((ext_vector_type(4)));
typedef float floatx2 __attribute__((ext_vector_type(2)));

// fast silu: native exp + fast div. rel-err ~1e-7, negligible vs fp16 rounding.
__device__ inline float silu_f(float x) {
    return __fdividef(x, 1.0f + __expf(-x));
}

// ---- prep 1: lat_part[b][j] = b0[j] + sum_d lat[b][d] * W0[d][j] ----
__global__ void prep_latw(const float* __restrict__ lat, const float* __restrict__ W0,
                          const float* __restrict__ b0, float* __restrict__ latw) {
    __shared__ float sl[H];
    const int b = blockIdx.x;
    const int j = threadIdx.x;
    sl[j] = lat[b * H + j];
    __syncthreads();
    float acc = b0[j];
#pragma unroll 8
    for (int d = 0; d < H; ++d) acc += sl[d] * W0[d * H + j];
    latw[b * H + j] = acc;
}

// ---- prep 2: W1/W2 -> fp16, fragment-major; chunk (l,kc) = 32KB contiguous ----
// kc=k>>5, q=(k>>3)&3, k0=k&7;  idx = (((l*16+kc)*4+q)*512 + n)*8 + k0
__global__ void prep_w16(const float* __restrict__ W1, const float* __restrict__ W2,
                         _Float16* __restrict__ ws) {
    const int id = blockIdx.x * 512 + threadIdx.x;   // 0 .. 524287
    const int l = id >> 18;
    const int rem = id & 0x3FFFF;                    // k*512 + n
    const int k = rem >> 9, n = rem & 511;
    const float w = (l == 0 ? W1 : W2)[rem];
    const int kc = k >> 5, q = (k >> 3) & 3, k0 = k & 7;
    ws[((size_t)((l * 16 + kc) * 4 + q) * 512 + n) * 8 + k0] = (_Float16)w;
}

// ---- main fused kernel ----
// R3: T3+T4 deep pipeline for the B stream.
//   B chunks (32KB per kc) staged global->LDS via global_load_lds (linear copy,
//   wsB already fragment-major-contiguous per chunk), double-buffered bs[2].
//   Counted vmcnt(4) waits (never 0 mid-loop) + raw s_barrier pairs per kc;
//   sched_barrier(0) pins motion (m201 template / rule #18/#21).
//   Prologue chunks for GEMM1 issued before layer 0; for GEMM2 before the
//   writeback -- HBM/L2 latency hides under VALU phases.
//   LDS 134 KB -> 1 block/CU, 8 waves (2/SIMD); reg-B buffers gone (off the
//   128-reg cliff), launch_bounds(512,2).
__global__ __launch_bounds__(512, 2) void mesh_main(
    const float* __restrict__ W0, const float* __restrict__ b1,
    const float* __restrict__ b2, const float* __restrict__ W3,
    const float* __restrict__ b3, const float* __restrict__ latw,
    const _Float16* __restrict__ wsB, float* __restrict__ out) {

    __shared__ _Float16 hbuf2[4096 * 8];          // 64 KB, fragment-major h
    __shared__ _Float16 bs[2][16384];             // 64 KB, B double-buffer
    __shared__ float lwbuf[2 * H];                // 4 KB
    __shared__ float partials[8][MTILE];          // 2 KB   -> 134 KB total

    const int tid = threadIdx.x;
    const int wave = tid >> 6, lane = tid & 63;
    const int q = lane >> 4, t = lane & 15;
    const int bi = blockIdx.x;
    const int b = bi >> 12;
    const int p0 = (bi & 4095) << 6;              // 64 rows per block (fixed x,y)
    const float c0 = -1.2f + (float)(p0 >> 12) * STEPC;
    const float c1 = -1.2f + (float)((p0 >> 6) & 63) * STEPC;

    // wave-cooperative stage of chunk (l,kc) into bs[buf]: 4 x 1KB per wave,
    // linear copy (LDS dest = uniform base + lane*16; src mirrors it).
    auto stage = [&](int buf, int l, int kc) {
        const _Float16* src = wsB + ((size_t)(l * 16 + kc) * 16384 + wave * 2048 + lane * 8);
        _Float16* dst = &bs[buf][wave * 2048];
#pragma unroll
        for (int i = 0; i < 4; ++i)
            __builtin_amdgcn_global_load_lds(
                (const __attribute__((address_space(1))) void*)(src + i * 512),
                (__attribute__((address_space(3))) void*)(dst + i * 512),
                16, 0, 0);
    };

    // GEMM1 prologue: chunks 0,1 of layer 0 in flight during layer-0 VALU
    stage(0, 0, 0);
    stage(1, 0, 1);

    // ---- layer 0, phase A: lw[j] = latw + c0*W0x + c1*W0y; w2c[j] = W0z ----
    {
        const int j = tid;
        const float lwv = latw[b * H + j]
                        + c0 * W0[(H + 0) * H + j]
                        + c1 * W0[(H + 1) * H + j];
        floatx2 v;
        v[0] = lwv;
        v[1] = W0[(H + 2) * H + j];
        *(floatx2*)&lwbuf[2 * j] = v;
    }
    __syncthreads();

    // ---- layer 0, phase B: row m = lane; regions g = wave*8+s ----
    {
        const float c2v = -1.2f + (float)lane * STEPC;
#pragma unroll
        for (int s = 0; s < 8; ++s) {
            const int g = wave * 8 + s;
            const floatx4* lp = (const floatx4*)&lwbuf[g * 16];  // broadcast reads
            half8 hv;
#pragma unroll
            for (int i = 0; i < 4; ++i) {
                const floatx4 pv = lp[i];          // (lw, w2c, lw, w2c)
                hv[2 * i + 0] = (_Float16)silu_f(pv[0] + c2v * pv[1]);
                hv[2 * i + 1] = (_Float16)silu_f(pv[2] + c2v * pv[3]);
            }
            *(half8*)&hbuf2[(g * 64 + lane) * 8] = hv;
        }
    }

    // per-lane bases
    const _Float16* hb = hbuf2 + q * 512 + t * 8;     // A fragments
    const int boff = q * 4096 + wave * 128 + t * 8;   // B fragment offset in chunk

    floatx4 acc[4][4];

    auto zero_acc = [&]() {
#pragma unroll
        for (int mf = 0; mf < 4; ++mf)
#pragma unroll
            for (int nt = 0; nt < 4; ++nt) {
                acc[mf][nt][0] = 0.f; acc[mf][nt][1] = 0.f;
                acc[mf][nt][2] = 0.f; acc[mf][nt][3] = 0.f;
            }
    };

    // one K-chunk phase: counted-vmcnt wait, barrier, ds_read A+B, 16 MFMA,
    // barrier, optional restage of kc+2 into the buffer just consumed.
    auto kphase = [&](int l, int kc, int buf, bool vm0, bool restage) {
        if (vm0) { asm volatile("s_waitcnt vmcnt(0)" ::: "memory"); }
        else     { asm volatile("s_waitcnt vmcnt(4)" ::: "memory"); }
        __builtin_amdgcn_sched_barrier(0);
        __builtin_amdgcn_s_barrier();            // all waves' chunk writes visible
        __builtin_amdgcn_sched_barrier(0);
        half8 bf[4], a[4];
        const _Float16* bp = &bs[buf][boff];
#pragma unroll
        for (int nt = 0; nt < 4; ++nt)
            bf[nt] = *(const half8*)(bp + nt * 1024);     // offset-imm folds
        const _Float16* hp = hb + kc * 2048;
#pragma unroll
        for (int mf = 0; mf < 4; ++mf)
            a[mf] = *(const half8*)(hp + mf * 128);
#pragma unroll
        for (int nt = 0; nt < 4; ++nt)
#pragma unroll
            for (int mf = 0; mf < 4; ++mf)
                acc[mf][nt] = __builtin_amdgcn_mfma_f32_16x16x32_f16(bf[nt], a[mf], acc[mf][nt], 0, 0, 0);
        __builtin_amdgcn_sched_barrier(0);
        __builtin_amdgcn_s_barrier();            // all waves done reading buf
        if (restage) stage(buf, l, kc + 2);      // loads stay in flight
    };

    auto run_gemm = [&](int l) {
#pragma unroll 1
        for (int kc = 0; kc < 14; kc += 2) {
            kphase(l, kc,     0, false, true);
            kphase(l, kc + 1, 1, false, true);
        }
        kphase(l, 14, 0, false, false);
        kphase(l, 15, 1, true,  false);          // drain: last chunk only
    };

    // ---- GEMM 1 ----
    zero_acc();
    __syncthreads();             // h0 ready (prologue loads long since landed)
    run_gemm(0);

    // GEMM2 prologue: issue now, lands under the writeback VALU
    stage(0, 1, 0);
    stage(1, 1, 1);

    // writeback h1 = silu(acc + b1): lane owns n = nt*128+wave*16+q*4 .. +3
    {
        const int R0 = (wave >> 1) * 4 + (wave & 1) * 2 + (q >> 1);
        _Float16* wb = hbuf2 + R0 * 512 + t * 8 + (q & 1) * 4;
        floatx4 b1v[4];
#pragma unroll
        for (int nt = 0; nt < 4; ++nt)
            b1v[nt] = *(const floatx4*)&b1[nt * 128 + wave * 16 + q * 4];
#pragma unroll
        for (int mf = 0; mf < 4; ++mf)
#pragma unroll
            for (int nt = 0; nt < 4; ++nt) {
                half4_t hv;
#pragma unroll
                for (int r = 0; r < 4; ++r)
                    hv[r] = (_Float16)silu_f(acc[mf][nt][r] + b1v[nt][r]);
                *(half4_t*)(wb + nt * 8192 + mf * 128) = hv;
            }
    }

    // ---- GEMM 2 ----
    zero_acc();
    __syncthreads();             // h1 ready (drains prologue: already landed)
    run_gemm(1);

    // ---- final layer: out = silu(acc + b2) @ W3 + b3, fp32 VALU ----
    {
        floatx4 b2v[4], w3v[4];
#pragma unroll
        for (int nt = 0; nt < 4; ++nt) {
            b2v[nt] = *(const floatx4*)&b2[nt * 128 + wave * 16 + q * 4];
            w3v[nt] = *(const floatx4*)&W3[nt * 128 + wave * 16 + q * 4];
        }
#pragma unroll
        for (int mf = 0; mf < 4; ++mf) {
            float sum = 0.f;
#pragma unroll
            for (int nt = 0; nt < 4; ++nt)
#pragma unroll
                for (int r = 0; r < 4; ++r)
                    sum += silu_f(acc[mf][nt][r] + b2v[nt][r]) * w3v[nt][r];
            sum += __shfl_xor(sum, 16);
            sum += __shfl_xor(sum, 32);
            if (lane < 16) partials[wave][mf * 16 + t] = sum;
        }
    }
    __syncthreads();
    if (tid < MTILE) {
        float o = b3[0];
#pragma unroll
        for (int w = 0; w < 8; ++w) o += partials[w][tid];
        out[(size_t)bi * MTILE + tid] = o;
    }
}

extern "C" void kernel_launch(void* const* d_in, const int* in_sizes, int n_in,
                              void* d_out, int out_size, void* d_ws, size_t ws_size,
                              hipStream_t stream) {
    const float* lat = (const float*)d_in[0];
    const float* W0  = (const float*)d_in[1];
    const float* b0  = (const float*)d_in[2];
    const float* W1  = (const float*)d_in[3];
    const float* b1  = (const float*)d_in[4];
    const float* W2  = (const float*)d_in[5];
    const float* b2  = (const float*)d_in[6];
    const float* W3  = (const float*)d_in[7];
    const float* b3  = (const float*)d_in[8];
    float* out = (float*)d_out;

    float* latw = (float*)d_ws;                               // 4 KB
    _Float16* wsB = (_Float16*)((char*)d_ws + 4096);          // 1 MB

    prep_latw<<<2, 512, 0, stream>>>(lat, W0, b0, latw);
    prep_w16<<<1024, 512, 0, stream>>>(W1, W2, wsB);
    mesh_main<<<NBLK, 512, 0, stream>>>(W0, b1, b2, W3, b3, latw, wsB, out);
}

// Round 4
// 835.791 us; speedup vs baseline: 1.3365x; 1.3365x over previous
//
#include <hip/hip_runtime.h>

#define H 512
#define MTILE 64
#define NBLK 8192
#define STEPC (2.4f / 63.0f)

typedef _Float16 half8 __attribute__((ext_vector_type(8)));
typedef _Float16 half4_t __attribute__((ext_vector_type(4)));
typedef float floatx16 __attribute__((ext_vector_type(16)));
typedef float floatx4 __attribute__((ext_vector_type(4)));
typedef float floatx2 __attribute__((ext_vector_type(2)));

// fast silu: native exp + fast div. rel-err ~1e-7, negligible vs fp16 rounding.
__device__ inline float silu_f(float x) {
    return __fdividef(x, 1.0f + __expf(-x));
}

// ---- prep 1: lat_part[b][j] = b0[j] + sum_d lat[b][d] * W0[d][j] ----
__global__ void prep_latw(const float* __restrict__ lat, const float* __restrict__ W0,
                          const float* __restrict__ b0, float* __restrict__ latw) {
    __shared__ float sl[H];
    const int b = blockIdx.x;
    const int j = threadIdx.x;
    sl[j] = lat[b * H + j];
    __syncthreads();
    float acc = b0[j];
#pragma unroll 8
    for (int d = 0; d < H; ++d) acc += sl[d] * W0[d * H + j];
    latw[b * H + j] = acc;
}

// ---- prep 2: W1/W2 -> fp16, fragment-major for 32x32x16 ----
// lane mapping (first operand): n = lane&31, k = (lane>>5)*8 + e
// image: idx = ((l*64 + (k>>3))*512 + n)*8 + (k&7)
__global__ void prep_w16(const float* __restrict__ W1, const float* __restrict__ W2,
                         _Float16* __restrict__ ws) {
    const int id = blockIdx.x * 512 + threadIdx.x;   // 0 .. 524287
    const int l = id >> 18;
    const int rem = id & 0x3FFFF;                    // k*512 + n
    const int k = rem >> 9, n = rem & 511;
    const float w = (l == 0 ? W1 : W2)[rem];
    ws[((size_t)(l * 64 + (k >> 3)) * 512 + n) * 8 + (k & 7)] = (_Float16)w;
}

// ---- main fused kernel ----
// R4: revert R3's LDS-stage pipeline (barrier pathology, m233). Back to the
// R2 structure (B from L2 into regs, barrier-free K-loop, fragment-major h
// in LDS) with ONE change: 32x32x16 MFMA instead of 16x16x32.
//   * matrix-pipe: 4060 vs 3378 FLOP/cyc (m119) -> -17% MFMA time
//   * MFMA issue count halved (256/wave/GEMM -> 128... 4 per K-step)
//   * per-wave tile 64x64 = 2mb x 2nt of 32x32, K-step 16:
//     2 ds_read_b128 (h) + 2 global b128 (W) + 4 MFMA per step, 32 steps
//   * h LDS layout UNCHANGED (region = col>>3); W image regrouped in prep.
//   * C/D (verified m74/m101): lane&31 = m, reg -> n=(reg&3)+8*(reg>>2)+4*hi
//     -> packed b64 epilogue writes, conflict-free; reduce = 1 shfl_xor(32).
// Regs: 4x2 half8 W-buffers (32 VGPR) + acc 2x2 floatx16 (64 AGPR): stays at
// 128-reg cliff, 4 waves/SIMD, 2 blocks/CU (70KB LDS). launch_bounds(512,4).
__global__ __launch_bounds__(512, 4) void mesh_main(
    const float* __restrict__ W0, const float* __restrict__ b1,
    const float* __restrict__ b2, const float* __restrict__ W3,
    const float* __restrict__ b3, const float* __restrict__ latw,
    const _Float16* __restrict__ wsB, float* __restrict__ out) {

    __shared__ _Float16 hbuf2[4096 * 8];          // 64 KB, fragment-major h
    __shared__ float lwbuf[2 * H];                // 4 KB
    __shared__ float partials[8][MTILE];          // 2 KB  -> 70 KB total

    const int tid = threadIdx.x;
    const int wave = tid >> 6, lane = tid & 63;
    const int lm = lane & 31, hi = lane >> 5;
    const int bi = blockIdx.x;
    const int b = bi >> 12;
    const int p0 = (bi & 4095) << 6;              // 64 rows per block (fixed x,y)
    const float c0 = -1.2f + (float)(p0 >> 12) * STEPC;
    const float c1 = -1.2f + (float)((p0 >> 6) & 63) * STEPC;

    // ---- layer 0, phase A: lw[j] = latw + c0*W0x + c1*W0y; w2c[j] = W0z ----
    {
        const int j = tid;
        const float lwv = latw[b * H + j]
                        + c0 * W0[(H + 0) * H + j]
                        + c1 * W0[(H + 1) * H + j];
        floatx2 v;
        v[0] = lwv;
        v[1] = W0[(H + 2) * H + j];
        *(floatx2*)&lwbuf[2 * j] = v;
    }
    __syncthreads();

    // ---- layer 0, phase B: row m = lane; regions g = wave*8+s ----
    {
        const float c2v = -1.2f + (float)lane * STEPC;
#pragma unroll
        for (int s = 0; s < 8; ++s) {
            const int g = wave * 8 + s;
            const floatx4* lp = (const floatx4*)&lwbuf[g * 16];  // broadcast reads
            half8 hv;
#pragma unroll
            for (int i = 0; i < 4; ++i) {
                const floatx4 pv = lp[i];          // (lw, w2c, lw, w2c)
                hv[2 * i + 0] = (_Float16)silu_f(pv[0] + c2v * pv[1]);
                hv[2 * i + 1] = (_Float16)silu_f(pv[2] + c2v * pv[3]);
            }
            *(half8*)&hbuf2[(g * 64 + lane) * 8] = hv;
        }
    }

    // per-lane bases: h (second operand, m = lm) and W (first operand, n)
    const _Float16* hb = hbuf2 + hi * 512 + lm * 8;
    const _Float16* wsl = wsB + ((size_t)hi * 512 + wave * 64 + lm) * 8;

    floatx16 acc[2][2];

    auto zero_acc = [&]() {
#pragma unroll
        for (int mb = 0; mb < 2; ++mb)
#pragma unroll
            for (int nt = 0; nt < 2; ++nt)
#pragma unroll
                for (int r = 0; r < 16; ++r) acc[mb][nt][r] = 0.f;
    };

    auto loadW = [&](int l, int ks, half8 (&wf)[2]) {
        const _Float16* p = wsl + (size_t)(l * 32 + ks) * 8192;
        wf[0] = *(const half8*)(p);            // nt=0
        wf[1] = *(const half8*)(p + 256);      // nt=1 (n += 32)
    };

    auto compute = [&](int ks, half8 (&wf)[2]) {
        half8 a[2];
        const _Float16* hp = hb + ks * 1024;
        a[0] = *(const half8*)(hp);            // mb=0, conflict-free b128
        a[1] = *(const half8*)(hp + 256);      // mb=1
#pragma unroll
        for (int nt = 0; nt < 2; ++nt)
#pragma unroll
            for (int mb = 0; mb < 2; ++mb)
                acc[mb][nt] = __builtin_amdgcn_mfma_f32_32x32x16_f16(wf[nt], a[mb], acc[mb][nt], 0, 0, 0);
    };

    // barrier-free K-loop, 2-step register lookahead on W (4 buffers, no copies)
    auto run_gemm = [&](int l) {
        half8 Wb0[2], Wb1[2], Wb2[2], Wb3[2];
        loadW(l, 0, Wb0);
        loadW(l, 1, Wb1);
#pragma unroll 1
        for (int ks = 0; ks < 32; ks += 4) {
            loadW(l, (ks + 2) & 31, Wb2);
            compute(ks, Wb0);
            loadW(l, (ks + 3) & 31, Wb3);
            compute(ks + 1, Wb1);
            loadW(l, (ks + 4) & 31, Wb0);      // wraps on last iter: harmless
            compute(ks + 2, Wb2);
            loadW(l, (ks + 5) & 31, Wb1);
            compute(ks + 3, Wb3);
        }
    };

    // ---- GEMM 1 ----
    zero_acc();
    __syncthreads();             // h0 ready
    run_gemm(0);
    __syncthreads();             // all waves done reading h0
    // writeback h1 = silu(acc + b1): lane owns, per (mb,nt,g), 4 consecutive
    // n = wave*64 + nt*32 + g*8 + hi*4 .. +3 at row m = mb*32+lm -> b64 writes
    {
        _Float16* wb = hbuf2 + (wave * 8) * 512 + lm * 8 + hi * 4;
        floatx4 b1v[2][4];
#pragma unroll
        for (int nt = 0; nt < 2; ++nt)
#pragma unroll
            for (int g = 0; g < 4; ++g)
                b1v[nt][g] = *(const floatx4*)&b1[wave * 64 + nt * 32 + g * 8 + hi * 4];
#pragma unroll
        for (int mb = 0; mb < 2; ++mb)
#pragma unroll
            for (int nt = 0; nt < 2; ++nt)
#pragma unroll
                for (int g = 0; g < 4; ++g) {
                    half4_t hv;
#pragma unroll
                    for (int j = 0; j < 4; ++j)
                        hv[j] = (_Float16)silu_f(acc[mb][nt][g * 4 + j] + b1v[nt][g][j]);
                    *(half4_t*)(wb + (nt * 4 + g) * 512 + mb * 256) = hv;
                }
    }

    // ---- GEMM 2 ----
    zero_acc();
    __syncthreads();             // h1 ready
    run_gemm(1);

    // ---- final layer: out = silu(acc + b2) @ W3 + b3, fp32 VALU ----
    {
        floatx4 b2v[2][4], w3v[2][4];
#pragma unroll
        for (int nt = 0; nt < 2; ++nt)
#pragma unroll
            for (int g = 0; g < 4; ++g) {
                const int n0 = wave * 64 + nt * 32 + g * 8 + hi * 4;
                b2v[nt][g] = *(const floatx4*)&b2[n0];
                w3v[nt][g] = *(const floatx4*)&W3[n0];
            }
#pragma unroll
        for (int mb = 0; mb < 2; ++mb) {
            float sum = 0.f;
#pragma unroll
            for (int nt = 0; nt < 2; ++nt)
#pragma unroll
                for (int g = 0; g < 4; ++g)
#pragma unroll
                    for (int j = 0; j < 4; ++j)
                        sum += silu_f(acc[mb][nt][g * 4 + j] + b2v[nt][g][j]) * w3v[nt][g][j];
            sum += __shfl_xor(sum, 32);        // combine hi halves (same m)
            if (hi == 0) partials[wave][mb * 32 + lm] = sum;
        }
    }
    __syncthreads();
    if (tid < MTILE) {
        float o = b3[0];
#pragma unroll
        for (int w = 0; w < 8; ++w) o += partials[w][tid];
        out[(size_t)bi * MTILE + tid] = o;
    }
}

extern "C" void kernel_launch(void* const* d_in, const int* in_sizes, int n_in,
                              void* d_out, int out_size, void* d_ws, size_t ws_size,
                              hipStream_t stream) {
    const float* lat = (const float*)d_in[0];
    const float* W0  = (const float*)d_in[1];
    const float* b0  = (const float*)d_in[2];
    const float* W1  = (const float*)d_in[3];
    const float* b1  = (const float*)d_in[4];
    const float* W2  = (const float*)d_in[5];
    const float* b2  = (const float*)d_in[6];
    const float* W3  = (const float*)d_in[7];
    const float* b3  = (const float*)d_in[8];
    float* out = (float*)d_out;

    float* latw = (float*)d_ws;                               // 4 KB
    _Float16* wsB = (_Float16*)((char*)d_ws + 4096);          // 1 MB

    prep_latw<<<2, 512, 0, stream>>>(lat, W0, b0, latw);
    prep_w16<<<1024, 512, 0, stream>>>(W1, W2, wsB);
    mesh_main<<<NBLK, 512, 0, stream>>>(W0, b1, b2, W3, b3, latw, wsB, out);
}